// Round 1
// baseline (370.940 us; speedup 1.0000x reference)
//
#include <hip/hip_runtime.h>
#include <math.h>

#define NTOK 96
#define EMBED 128
#define HEADS 4
#define HD 32
#define NROW (NTOK*NTOK)   // 9216

// K1: p = x @ W + b ; pn = headwise LayerNorm(p)
__global__ __launch_bounds__(128) void k_proj(
        const float* __restrict__ x, const float* __restrict__ W,
        const float* __restrict__ b, const float* __restrict__ ln_g,
        const float* __restrict__ ln_b,
        float* __restrict__ p, float* __restrict__ pn) {
    const int row = blockIdx.x;       // x*96+y
    const int e = threadIdx.x;        // 0..127
    __shared__ float xr[EMBED];
    xr[e] = x[(size_t)row * EMBED + e];
    __syncthreads();

    float acc = b[e];
    #pragma unroll 8
    for (int i = 0; i < EMBED; ++i)
        acc = fmaf(xr[i], W[i * EMBED + e], acc);

    // LayerNorm over 32-wide head groups (aligned inside the 64-wave)
    float s1 = acc, s2 = acc * acc;
    #pragma unroll
    for (int m = 1; m < 32; m <<= 1) {
        s1 += __shfl_xor(s1, m, 64);
        s2 += __shfl_xor(s2, m, 64);
    }
    float mu = s1 * (1.f / HD);
    float var = s2 * (1.f / HD) - mu * mu;
    float rstd = rsqrtf(var + 1e-5f);
    int d = e & (HD - 1);
    p[(size_t)row * EMBED + e] = acc;
    pn[(size_t)row * EMBED + e] = (acc - mu) * rstd * ln_g[d] + ln_b[d];
}

// K2: everything else, one block per (x,y) output row.
__global__ __launch_bounds__(256) void k_main(
        const float* __restrict__ x,
        const float* __restrict__ p, const float* __restrict__ pn,
        const float* __restrict__ ln_g, const float* __restrict__ ln_b,
        const float* __restrict__ Wf, const float* __restrict__ bf,
        const float* __restrict__ g2, const float* __restrict__ b2,
        float* __restrict__ out) {
    const int bx = blockIdx.x / NTOK;   // x index
    const int by = blockIdx.x % NTOK;   // y index
    const int tid = threadIdx.x;
    const int h = tid >> 6;             // wave id == head
    const int lane = tid & 63;

    __shared__ float s_sm[HEADS][NTOK];
    __shared__ float r_sm[HEADS][NTOK];
    __shared__ float mu_sm[HEADS][NTOK];
    __shared__ float w_sm[HEADS][NTOK];
    __shared__ float cd_sm[HEADS][2];
    __shared__ float agg_sm[EMBED];
    __shared__ float xr_sm[EMBED];
    __shared__ float red_sm[2][2];

    if (tid < EMBED) xr_sm[tid] = x[(size_t)blockIdx.x * EMBED + tid];

    // ---- pass 1: per-a dot products (lane = a) ----
    #pragma unroll
    for (int it = 0; it < 2; ++it) {
        int a = lane + it * 64;
        if (a < NTOK) {
            const float4* pe  = (const float4*)(p  + ((size_t)(bx * NTOK + a) * HEADS + h) * HD);
            const float4* pf  = (const float4*)(p  + ((size_t)(a * NTOK + by) * HEADS + h) * HD);
            const float4* pen = (const float4*)(pn + ((size_t)(bx * NTOK + a) * HEADS + h) * HD);
            const float4* pfn = (const float4*)(pn + ((size_t)(a * NTOK + by) * HEADS + h) * HD);
            float s = 0.f, m = 0.f, q = 0.f;
            #pragma unroll
            for (int j = 0; j < HD / 4; ++j) {
                float4 e4 = pe[j], f4 = pf[j], en4 = pen[j], fn4 = pfn[j];
                s += en4.x * fn4.x + en4.y * fn4.y + en4.z * fn4.z + en4.w * fn4.w;
                float tx = e4.x * f4.x, ty = e4.y * f4.y,
                      tz = e4.z * f4.z, tw = e4.w * f4.w;
                m += tx + ty + tz + tw;
                q += tx * tx + ty * ty + tz * tz + tw * tw;
            }
            float mu = m * (1.f / HD);
            float var = q * (1.f / HD) - mu * mu;
            s_sm[h][a]  = s * 0.17677669529663687f;  // 1/sqrt(32)
            r_sm[h][a]  = rsqrtf(var + 1e-5f);
            mu_sm[h][a] = mu;
        }
    }
    __syncthreads();

    // ---- softmax over a (per head, within its wave) ----
    {
        int a1 = 64 + (lane & 31);
        float s0 = s_sm[h][lane];
        float s1 = (lane < 32) ? s_sm[h][a1] : -1e30f;
        float mx = fmaxf(s0, s1);
        #pragma unroll
        for (int m_ = 1; m_ < 64; m_ <<= 1) mx = fmaxf(mx, __shfl_xor(mx, m_, 64));
        float e0 = __expf(s0 - mx);
        float e1 = (lane < 32) ? __expf(s1 - mx) : 0.f;
        float r0 = r_sm[h][lane],  m0 = mu_sm[h][lane];
        float r1 = r_sm[h][a1],    m1 = mu_sm[h][a1];
        if (lane >= 32) { r1 = 0.f; m1 = 0.f; }
        float den = e0 + e1;
        float c   = e0 * r0 * m0 + e1 * r1 * m1;
        #pragma unroll
        for (int m_ = 1; m_ < 64; m_ <<= 1) {
            den += __shfl_xor(den, m_, 64);
            c   += __shfl_xor(c,   m_, 64);
        }
        w_sm[h][lane] = e0 * r0;
        if (lane < 32) w_sm[h][a1] = e1 * r1;
        if (lane == 0) { cd_sm[h][0] = c; cd_sm[h][1] = den; }
    }
    __syncthreads();

    // ---- pass 2: weighted aggregation (lane = d, two a-halves) ----
    {
        int g  = lane >> 5;
        int dd = lane & 31;
        float acc = 0.f;
        int a0 = g * 48, a1 = a0 + 48;
        for (int a = a0; a < a1; ++a) {
            float w = w_sm[h][a];
            float e = p[((size_t)(bx * NTOK + a) * HEADS + h) * HD + dd];
            float f = p[((size_t)(a * NTOK + by) * HEADS + h) * HD + dd];
            acc = fmaf(w, e * f, acc);
        }
        acc += __shfl_xor(acc, 32, 64);
        if (g == 0) {
            float c = cd_sm[h][0], den = cd_sm[h][1];
            agg_sm[h * HD + dd] = ln_g[dd] * (acc - c) / den + ln_b[dd];
        }
    }
    __syncthreads();

    // ---- final: out = [x, agg] @ Wf + bf, then LN over 128 ----
    float acc = 0.f;
    if (tid < EMBED) {
        const int e = tid;
        acc = bf[e];
        #pragma unroll 4
        for (int i = 0; i < EMBED; ++i)
            acc = fmaf(xr_sm[i], Wf[i * EMBED + e], acc);
        #pragma unroll 4
        for (int d = 0; d < EMBED; ++d)
            acc = fmaf(agg_sm[d], Wf[(EMBED + d) * EMBED + e], acc);
        float s1 = acc, s2 = acc * acc;
        #pragma unroll
        for (int m_ = 1; m_ < 64; m_ <<= 1) {
            s1 += __shfl_xor(s1, m_, 64);
            s2 += __shfl_xor(s2, m_, 64);
        }
        int w = tid >> 6;
        if ((tid & 63) == 0) { red_sm[w][0] = s1; red_sm[w][1] = s2; }
    }
    __syncthreads();
    if (tid < EMBED) {
        float S1 = red_sm[0][0] + red_sm[1][0];
        float S2 = red_sm[0][1] + red_sm[1][1];
        float mu = S1 * (1.f / EMBED);
        float var = S2 * (1.f / EMBED) - mu * mu;
        float rstd = rsqrtf(var + 1e-5f);
        out[(size_t)blockIdx.x * EMBED + tid] =
            (acc - mu) * rstd * g2[tid] + b2[tid];
    }
}

extern "C" void kernel_launch(void* const* d_in, const int* in_sizes, int n_in,
                              void* d_out, int out_size, void* d_ws, size_t ws_size,
                              hipStream_t stream) {
    const float* x    = (const float*)d_in[0];
    const float* W    = (const float*)d_in[1];
    const float* b    = (const float*)d_in[2];
    const float* ln_g = (const float*)d_in[3];
    const float* ln_b = (const float*)d_in[4];
    const float* Wf   = (const float*)d_in[5];
    const float* bf   = (const float*)d_in[6];
    const float* g2   = (const float*)d_in[7];
    const float* b2   = (const float*)d_in[8];
    float* out = (float*)d_out;

    float* p  = (float*)d_ws;                 // 9216*128 floats
    float* pn = p + (size_t)NROW * EMBED;     // 9216*128 floats

    k_proj<<<NROW, 128, 0, stream>>>(x, W, b, ln_g, ln_b, p, pn);
    k_main<<<NROW, 256, 0, stream>>>(x, p, pn, ln_g, ln_b, Wf, bf, g2, b2, out);
}

// Round 2
// 237.626 us; speedup vs baseline: 1.5610x; 1.5610x over previous
//
#include <hip/hip_runtime.h>
#include <math.h>

#define NTOK 96
#define EMBED 128
#define HEADS 4
#define HD 32
#define NROW (NTOK*NTOK)     // 9216
#define YT 16
#define NYT (NTOK/YT)        // 6
#define RPB 16               // rows per block (proj/final)
#define NBLK (NROW/RPB)      // 576

// ---------------- K1: p = x@W + b, plus per-(row,head) LN stats ----------------
__global__ __launch_bounds__(128) void k_proj(
    const float* __restrict__ x, const float* __restrict__ W,
    const float* __restrict__ b,
    float* __restrict__ p, float* __restrict__ mur) {
  const int r0 = blockIdx.x * RPB;
  const int e = threadIdx.x;             // 0..127 (output column)
  __shared__ float xt[EMBED][20];        // transposed activations, stride 20
  #pragma unroll
  for (int k = 0; k < RPB; ++k)
    xt[e][k] = x[(size_t)(r0 + k) * EMBED + e];
  __syncthreads();

  float acc[RPB];
  const float bias = b[e];
  #pragma unroll
  for (int k = 0; k < RPB; ++k) acc[k] = bias;

  #pragma unroll 4
  for (int i = 0; i < EMBED; ++i) {
    const float wv = W[(size_t)i * EMBED + e];
    const float4 c0 = *(const float4*)&xt[i][0];
    const float4 c1 = *(const float4*)&xt[i][4];
    const float4 c2 = *(const float4*)&xt[i][8];
    const float4 c3 = *(const float4*)&xt[i][12];
    acc[0]  = fmaf(wv, c0.x, acc[0]);  acc[1]  = fmaf(wv, c0.y, acc[1]);
    acc[2]  = fmaf(wv, c0.z, acc[2]);  acc[3]  = fmaf(wv, c0.w, acc[3]);
    acc[4]  = fmaf(wv, c1.x, acc[4]);  acc[5]  = fmaf(wv, c1.y, acc[5]);
    acc[6]  = fmaf(wv, c1.z, acc[6]);  acc[7]  = fmaf(wv, c1.w, acc[7]);
    acc[8]  = fmaf(wv, c2.x, acc[8]);  acc[9]  = fmaf(wv, c2.y, acc[9]);
    acc[10] = fmaf(wv, c2.z, acc[10]); acc[11] = fmaf(wv, c2.w, acc[11]);
    acc[12] = fmaf(wv, c3.x, acc[12]); acc[13] = fmaf(wv, c3.y, acc[13]);
    acc[14] = fmaf(wv, c3.z, acc[14]); acc[15] = fmaf(wv, c3.w, acc[15]);
  }

  const int h = e >> 5;
  #pragma unroll
  for (int k = 0; k < RPB; ++k) {
    p[(size_t)(r0 + k) * EMBED + e] = acc[k];
    float s1 = acc[k], s2 = acc[k] * acc[k];
    #pragma unroll
    for (int m_ = 1; m_ < 32; m_ <<= 1) {
      s1 += __shfl_xor(s1, m_, 64);
      s2 += __shfl_xor(s2, m_, 64);
    }
    if ((e & 31) == 0) {
      const float mu = s1 * (1.f / HD);
      const float var = s2 * (1.f / HD) - mu * mu;
      float2 v; v.x = mu; v.y = rsqrtf(var + 1e-5f);
      *(float2*)&mur[((size_t)(r0 + k) * HEADS + h) * 2] = v;
    }
  }
}

__device__ __forceinline__ void p1_comp(float e, float f, float g, float b,
    float muE, float rE, float muF, float rF,
    float& s, float& m, float& q) {
  const float u  = (e - muE) * rE;
  const float en = fmaf(u, g, b);
  const float v  = (f - muF) * rF;
  const float fn = fmaf(v, g, b);
  s = fmaf(en, fn, s);
  const float t = e * f;
  m += t;
  q = fmaf(t, t, q);
}

// ---------------- K2: scores+softmax+fused x_upd-LN aggregation ----------------
// block = (x, y-tile of 16, head-pair); 256 threads = (h:2, y:16, da/dq:8)
__global__ __launch_bounds__(256, 3) void k_attn(
    const float* __restrict__ p, const float* __restrict__ mur,
    const float* __restrict__ ln_g, const float* __restrict__ ln_b,
    float* __restrict__ agg) {
  const int X   = blockIdx.x;
  const int y0  = blockIdx.y * YT;
  const int hp  = blockIdx.z;
  const int tid = threadIdx.x;
  const int h   = tid >> 7;         // local head in pair: 0..1
  const int y   = (tid >> 3) & 15;  // 0..15
  const int da  = tid & 7;          // a-slice / d-quad
  const int H   = hp * 2 + h;       // global head 0..3
  const int yy  = y0 + y;

  __shared__ float e_sm[NTOK][68];       // p[x,a, hp*64 + j]  (26.1 KB)
  __shared__ float murE_sm[NTOK][2][2];  // e-row stats (local heads)
  __shared__ float w_sm[2][YT][97];      // softmax*rstd weights
  __shared__ float cd_sm[2][YT][2];      // c, den
  __shared__ float g_sm[HD], b_sm[HD];

  // ---- stage ----
  #pragma unroll
  for (int k = 0; k < 6; ++k) {
    const int v = tid + k * 256;
    const int a = v >> 4, qq = v & 15;
    *(float4*)&e_sm[a][qq * 4] =
        *(const float4*)&p[((size_t)(X * NTOK + a) * EMBED) + hp * 64 + qq * 4];
  }
  if (tid < 192) {
    const int a = tid >> 1, hh = tid & 1;
    const float2 v = *(const float2*)&mur[((size_t)(X * NTOK + a) * HEADS + hp * 2 + hh) * 2];
    murE_sm[a][hh][0] = v.x; murE_sm[a][hh][1] = v.y;
  }
  if (tid < HD) { g_sm[tid] = ln_g[tid]; b_sm[tid] = ln_b[tid]; }
  __syncthreads();

  // ---- pass 1: per-a score dot + product moments (lane owns 12 a's) ----
  float sreg[12], rreg[12], mreg[12];
  #pragma unroll
  for (int ia = 0; ia < 12; ++ia) {
    const int a = da + ia * 8;
    const float4* fp = (const float4*)(p + ((size_t)(a * NTOK + yy)) * EMBED + H * HD);
    const float2 mrF = *(const float2*)&mur[((size_t)(a * NTOK + yy) * HEADS + H) * 2];
    const float muE = murE_sm[a][h][0], rE = murE_sm[a][h][1];
    float s = 0.f, m = 0.f, q = 0.f;
    #pragma unroll
    for (int j = 0; j < 8; ++j) {
      const float4 f4 = fp[j];
      const float4 e4 = *(const float4*)&e_sm[a][h * HD + j * 4];
      const float4 g4 = *(const float4*)&g_sm[j * 4];
      const float4 b4 = *(const float4*)&b_sm[j * 4];
      p1_comp(e4.x, f4.x, g4.x, b4.x, muE, rE, mrF.x, mrF.y, s, m, q);
      p1_comp(e4.y, f4.y, g4.y, b4.y, muE, rE, mrF.x, mrF.y, s, m, q);
      p1_comp(e4.z, f4.z, g4.z, b4.z, muE, rE, mrF.x, mrF.y, s, m, q);
      p1_comp(e4.w, f4.w, g4.w, b4.w, muE, rE, mrF.x, mrF.y, s, m, q);
    }
    const float mu = m * (1.f / HD);
    const float var = fmaf(-mu, mu, q * (1.f / HD));
    sreg[ia] = s * 0.17677669529663687f;   // 1/sqrt(32)
    rreg[ia] = rsqrtf(var + 1e-5f);
    mreg[ia] = mu;
  }

  // ---- softmax over a within 8-lane (h,y) group ----
  float mx = sreg[0];
  #pragma unroll
  for (int ia = 1; ia < 12; ++ia) mx = fmaxf(mx, sreg[ia]);
  #pragma unroll
  for (int m_ = 1; m_ < 8; m_ <<= 1) mx = fmaxf(mx, __shfl_xor(mx, m_, 64));
  float den = 0.f, c = 0.f;
  float wreg[12];
  #pragma unroll
  for (int ia = 0; ia < 12; ++ia) {
    const float ex = __expf(sreg[ia] - mx);
    den += ex;
    const float wr = ex * rreg[ia];
    wreg[ia] = wr;
    c = fmaf(wr, mreg[ia], c);
  }
  #pragma unroll
  for (int m_ = 1; m_ < 8; m_ <<= 1) {
    den += __shfl_xor(den, m_, 64);
    c   += __shfl_xor(c,   m_, 64);
  }
  #pragma unroll
  for (int ia = 0; ia < 12; ++ia)
    w_sm[h][y][ia * 8 + da] = wreg[ia];
  if (da == 0) { cd_sm[h][y][0] = c; cd_sm[h][y][1] = den; }
  __syncthreads();

  // ---- pass 2: weighted aggregation (lane owns a 4-wide d quad) ----
  const int dq = da;
  float4 acc = {0.f, 0.f, 0.f, 0.f};
  const float* w_row = &w_sm[h][y][0];
  #pragma unroll 4
  for (int a = 0; a < NTOK; ++a) {
    const float w = w_row[a];
    const float4 e4 = *(const float4*)&e_sm[a][h * HD + dq * 4];
    const float4 f4 = *(const float4*)(p + ((size_t)(a * NTOK + yy)) * EMBED + H * HD + dq * 4);
    acc.x = fmaf(w * e4.x, f4.x, acc.x);
    acc.y = fmaf(w * e4.y, f4.y, acc.y);
    acc.z = fmaf(w * e4.z, f4.z, acc.z);
    acc.w = fmaf(w * e4.w, f4.w, acc.w);
  }
  const float cc  = cd_sm[h][y][0];
  const float inv = 1.f / cd_sm[h][y][1];
  const float4 g4 = *(const float4*)&g_sm[dq * 4];
  const float4 b4 = *(const float4*)&b_sm[dq * 4];
  float4 o;
  o.x = fmaf(g4.x, (acc.x - cc) * inv, b4.x);
  o.y = fmaf(g4.y, (acc.y - cc) * inv, b4.y);
  o.z = fmaf(g4.z, (acc.z - cc) * inv, b4.z);
  o.w = fmaf(g4.w, (acc.w - cc) * inv, b4.w);
  *(float4*)&agg[((size_t)(X * NTOK + yy)) * EMBED + H * HD + dq * 4] = o;
}

// ---------------- K3: out = LN([x, agg] @ Wf + bf) ----------------
__global__ __launch_bounds__(256) void k_final(
    const float* __restrict__ x, const float* __restrict__ agg,
    const float* __restrict__ Wf, const float* __restrict__ bf,
    const float* __restrict__ g2, const float* __restrict__ b2,
    float* __restrict__ out) {
  const int r0 = blockIdx.x * RPB;
  const int tid = threadIdx.x;
  const int e = tid & 127;
  const int rg = tid >> 7;               // row group: 8 rows each
  __shared__ float ct[2 * EMBED][20];    // transposed [x|agg], stride 20
  __shared__ float red[2][8][2][2];

  #pragma unroll
  for (int k = 0; k < RPB; ++k) {
    const float v = (tid < EMBED) ? x[(size_t)(r0 + k) * EMBED + tid]
                                  : agg[(size_t)(r0 + k) * EMBED + (tid - EMBED)];
    ct[tid][k] = v;
  }
  __syncthreads();

  float acc[8];
  const float bias = bf[e];
  #pragma unroll
  for (int k = 0; k < 8; ++k) acc[k] = bias;

  #pragma unroll 4
  for (int i = 0; i < 2 * EMBED; ++i) {
    const float wv = Wf[(size_t)i * EMBED + e];
    const float4 c0 = *(const float4*)&ct[i][rg * 8];
    const float4 c1 = *(const float4*)&ct[i][rg * 8 + 4];
    acc[0] = fmaf(wv, c0.x, acc[0]); acc[1] = fmaf(wv, c0.y, acc[1]);
    acc[2] = fmaf(wv, c0.z, acc[2]); acc[3] = fmaf(wv, c0.w, acc[3]);
    acc[4] = fmaf(wv, c1.x, acc[4]); acc[5] = fmaf(wv, c1.y, acc[5]);
    acc[6] = fmaf(wv, c1.z, acc[6]); acc[7] = fmaf(wv, c1.w, acc[7]);
  }

  const int wh = (tid >> 6) & 1;
  #pragma unroll
  for (int k = 0; k < 8; ++k) {
    float s1 = acc[k], s2 = acc[k] * acc[k];
    #pragma unroll
    for (int m_ = 1; m_ < 64; m_ <<= 1) {
      s1 += __shfl_xor(s1, m_, 64);
      s2 += __shfl_xor(s2, m_, 64);
    }
    if ((tid & 63) == 0) { red[rg][k][wh][0] = s1; red[rg][k][wh][1] = s2; }
  }
  __syncthreads();

  const float gg = g2[e], bb = b2[e];
  #pragma unroll
  for (int k = 0; k < 8; ++k) {
    const float S1 = red[rg][k][0][0] + red[rg][k][1][0];
    const float S2 = red[rg][k][0][1] + red[rg][k][1][1];
    const float mu = S1 * (1.f / EMBED);
    const float var = S2 * (1.f / EMBED) - mu * mu;
    const float rstd = rsqrtf(var + 1e-5f);
    out[(size_t)(r0 + rg * 8 + k) * EMBED + e] = (acc[k] - mu) * rstd * gg + bb;
  }
}

extern "C" void kernel_launch(void* const* d_in, const int* in_sizes, int n_in,
                              void* d_out, int out_size, void* d_ws, size_t ws_size,
                              hipStream_t stream) {
  const float* x    = (const float*)d_in[0];
  const float* W    = (const float*)d_in[1];
  const float* b    = (const float*)d_in[2];
  const float* ln_g = (const float*)d_in[3];
  const float* ln_b = (const float*)d_in[4];
  const float* Wf   = (const float*)d_in[5];
  const float* bf   = (const float*)d_in[6];
  const float* g2   = (const float*)d_in[7];
  const float* b2   = (const float*)d_in[8];
  float* out = (float*)d_out;

  float* p   = (float*)d_ws;                       // NROW*128
  float* mur = p + (size_t)NROW * EMBED;           // NROW*4*2
  float* agg = mur + (size_t)NROW * HEADS * 2;     // NROW*128

  k_proj<<<NBLK, 128, 0, stream>>>(x, W, b, p, mur);
  k_attn<<<dim3(NTOK, NYT, 2), 256, 0, stream>>>(p, mur, ln_g, ln_b, agg);
  k_final<<<NBLK, 256, 0, stream>>>(x, agg, Wf, bf, g2, b2, out);
}

// Round 3
// 154.417 us; speedup vs baseline: 2.4022x; 1.5389x over previous
//
#include <hip/hip_runtime.h>
#include <math.h>

#define NTOK 96
#define EMBED 128
#define HEADS 4
#define HD 32
#define NROW (NTOK*NTOK)     // 9216
#define YT 16
#define NYT (NTOK/YT)        // 6
#define RPB 16               // rows per block (proj/final)
#define NBLK (NROW/RPB)      // 576
#define AC 8                 // a-chunk
#define NCH (NTOK/AC)        // 12

// ---------------- K1: pT[(y*96+x)] = row(x,y) of x@W+b ; murT stats ----------------
__global__ __launch_bounds__(128) void k_proj(
    const float* __restrict__ x, const float* __restrict__ W,
    const float* __restrict__ b,
    float* __restrict__ pT, float* __restrict__ murT) {
  const int r0 = blockIdx.x * RPB;       // rows (X, y0..y0+15)
  const int X  = r0 / NTOK;
  const int y0 = r0 % NTOK;
  const int e = threadIdx.x;             // 0..127
  __shared__ float xt[EMBED][20];
  #pragma unroll
  for (int k = 0; k < RPB; ++k)
    xt[e][k] = x[(size_t)(r0 + k) * EMBED + e];
  __syncthreads();

  float acc[RPB];
  const float bias = b[e];
  #pragma unroll
  for (int k = 0; k < RPB; ++k) acc[k] = bias;

  #pragma unroll 4
  for (int i = 0; i < EMBED; ++i) {
    const float wv = W[(size_t)i * EMBED + e];
    const float4 c0 = *(const float4*)&xt[i][0];
    const float4 c1 = *(const float4*)&xt[i][4];
    const float4 c2 = *(const float4*)&xt[i][8];
    const float4 c3 = *(const float4*)&xt[i][12];
    acc[0]  = fmaf(wv, c0.x, acc[0]);  acc[1]  = fmaf(wv, c0.y, acc[1]);
    acc[2]  = fmaf(wv, c0.z, acc[2]);  acc[3]  = fmaf(wv, c0.w, acc[3]);
    acc[4]  = fmaf(wv, c1.x, acc[4]);  acc[5]  = fmaf(wv, c1.y, acc[5]);
    acc[6]  = fmaf(wv, c1.z, acc[6]);  acc[7]  = fmaf(wv, c1.w, acc[7]);
    acc[8]  = fmaf(wv, c2.x, acc[8]);  acc[9]  = fmaf(wv, c2.y, acc[9]);
    acc[10] = fmaf(wv, c2.z, acc[10]); acc[11] = fmaf(wv, c2.w, acc[11]);
    acc[12] = fmaf(wv, c3.x, acc[12]); acc[13] = fmaf(wv, c3.y, acc[13]);
    acc[14] = fmaf(wv, c3.z, acc[14]); acc[15] = fmaf(wv, c3.w, acc[15]);
  }

  const int h = e >> 5;
  #pragma unroll
  for (int k = 0; k < RPB; ++k) {
    pT[((size_t)(y0 + k) * NTOK + X) * EMBED + e] = acc[k];
    float s1 = acc[k], s2 = acc[k] * acc[k];
    #pragma unroll
    for (int m_ = 1; m_ < 32; m_ <<= 1) {
      s1 += __shfl_xor(s1, m_, 64);
      s2 += __shfl_xor(s2, m_, 64);
    }
    if ((e & 31) == 0) {
      const float mu = s1 * (1.f / HD);
      const float var = s2 * (1.f / HD) - mu * mu;
      float2 v; v.x = mu; v.y = rsqrtf(var + 1e-5f);
      *(float2*)&murT[(((size_t)(y0 + k) * NTOK + X) * HEADS + h) * 2] = v;
    }
  }
}

__device__ __forceinline__ void p1_comp(float e, float f, float g, float b,
    float muE, float rE, float muF, float rF,
    float& s, float& m, float& q) {
  const float en = fmaf((e - muE) * rE, g, b);
  const float fn = fmaf((f - muF) * rF, g, b);
  s = fmaf(en, fn, s);
  const float t = e * f;
  m += t;
  q = fmaf(t, t, q);
}

// ---------------- K2: online-softmax fused attention+product-LN ----------------
// 1152 blocks (X:96, ytile:6, hp:2) swizzled so hp is pinned per XCD half.
// 256 threads = (h:2, y:16, da:8)
__global__ __launch_bounds__(256) void k_attn(
    const float* __restrict__ pT, const float* __restrict__ murT,
    const float* __restrict__ ln_g, const float* __restrict__ ln_b,
    float* __restrict__ agg) {
  const int bid = blockIdx.x;
  const int xcd = bid & 7;
  const int hp  = xcd >> 2;                       // XCD 0-3 -> hp0, 4-7 -> hp1
  const int idx = (bid >> 3) * 4 + (xcd & 3);     // 0..575
  const int X   = idx / NYT;
  const int y0  = (idx % NYT) * YT;

  const int tid  = threadIdx.x;
  const int h    = tid >> 7;        // local head in pair
  const int y    = (tid >> 3) & 15;
  const int da   = tid & 7;
  const int lane = tid & 63;
  const int H    = hp * 2 + h;
  const int yy   = y0 + y;

  __shared__ float e_sm[NTOK][68];    // 26112 B : p[x=X, a, hp slice]
  __shared__ float f_sm[YT][AC][68];  // 34816 B : p[a-chunk, y-tile, hp slice]
  __shared__ float g_sm[HD], b_sm[HD];

  // stage e-side (rows (a*96+X) of pT) — coalesced 256B spans
  #pragma unroll
  for (int i = 0; i < 6; ++i) {
    const int g = tid + i * 256;       // 0..1535
    const int a = g >> 4, qq = g & 15;
    *(float4*)&e_sm[a][qq * 4] =
        *(const float4*)&pT[((size_t)a * NTOK + X) * EMBED + hp * 64 + qq * 4];
  }
  if (tid < HD) { g_sm[tid] = ln_g[tid]; b_sm[tid] = ln_b[tid]; }

  float mx = -1e30f, den = 0.f, c = 0.f;
  float4 acc = {0.f, 0.f, 0.f, 0.f};
  const int gbase = lane & 56;

  for (int ch = 0; ch < NCH; ++ch) {
    __syncthreads();   // protect f_sm readers (and e_sm stage on ch==0)
    // stage f chunk: rows ((y0+yy)*96 + ch*8+la), coalesced
    #pragma unroll
    for (int i = 0; i < 8; ++i) {
      const int g = tid + i * 256;     // 0..2047
      const int row = g >> 4, qq = g & 15;
      const int yl = row >> 3, la = row & 7;
      *(float4*)&f_sm[yl][la][qq * 4] =
          *(const float4*)&pT[((size_t)(y0 + yl) * NTOK + ch * AC + la) * EMBED + hp * 64 + qq * 4];
    }
    __syncthreads();

    // ---- score + product moments for a = ch*8 + da ----
    const int a = ch * AC + da;
    const float2 mrE = *(const float2*)&murT[(((size_t)a * NTOK + X) * HEADS + H) * 2];
    const float2 mrF = *(const float2*)&murT[(((size_t)yy * NTOK + a) * HEADS + H) * 2];
    float s = 0.f, m = 0.f, q = 0.f;
    #pragma unroll
    for (int j = 0; j < 8; ++j) {
      const float4 e4 = *(const float4*)&e_sm[a][h * HD + j * 4];
      const float4 f4 = *(const float4*)&f_sm[y][da][h * HD + j * 4];
      const float4 g4 = *(const float4*)&g_sm[j * 4];
      const float4 b4 = *(const float4*)&b_sm[j * 4];
      p1_comp(e4.x, f4.x, g4.x, b4.x, mrE.x, mrE.y, mrF.x, mrF.y, s, m, q);
      p1_comp(e4.y, f4.y, g4.y, b4.y, mrE.x, mrE.y, mrF.x, mrF.y, s, m, q);
      p1_comp(e4.z, f4.z, g4.z, b4.z, mrE.x, mrE.y, mrF.x, mrF.y, s, m, q);
      p1_comp(e4.w, f4.w, g4.w, b4.w, mrE.x, mrE.y, mrF.x, mrF.y, s, m, q);
    }
    const float mu = m * (1.f / HD);
    const float var = fmaf(-mu, mu, q * (1.f / HD));
    const float r = rsqrtf(var + 1e-5f);
    s *= 0.17677669529663687f;   // 1/sqrt(32)

    // ---- online softmax update within 8-lane (h,y) group ----
    float mc = s;
    mc = fmaxf(mc, __shfl_xor(mc, 1, 64));
    mc = fmaxf(mc, __shfl_xor(mc, 2, 64));
    mc = fmaxf(mc, __shfl_xor(mc, 4, 64));
    const float nmx = fmaxf(mx, mc);
    const float scale = __expf(mx - nmx);
    const float ex = __expf(s - nmx);
    const float w = ex * r;
    float dsum = ex, csum = w * mu;
    dsum += __shfl_xor(dsum, 1, 64);  csum += __shfl_xor(csum, 1, 64);
    dsum += __shfl_xor(dsum, 2, 64);  csum += __shfl_xor(csum, 2, 64);
    dsum += __shfl_xor(dsum, 4, 64);  csum += __shfl_xor(csum, 4, 64);
    den = fmaf(den, scale, dsum);
    c   = fmaf(c,   scale, csum);
    acc.x *= scale; acc.y *= scale; acc.z *= scale; acc.w *= scale;
    mx = nmx;

    // ---- aggregation over this chunk (lane owns d-quad da) ----
    #pragma unroll
    for (int la = 0; la < AC; ++la) {
      const float wl = __shfl(w, gbase | la, 64);
      const float4 e4 = *(const float4*)&e_sm[ch * AC + la][h * HD + da * 4];
      const float4 f4 = *(const float4*)&f_sm[y][la][h * HD + da * 4];
      acc.x = fmaf(wl * e4.x, f4.x, acc.x);
      acc.y = fmaf(wl * e4.y, f4.y, acc.y);
      acc.z = fmaf(wl * e4.z, f4.z, acc.z);
      acc.w = fmaf(wl * e4.w, f4.w, acc.w);
    }
  }

  // ---- epilogue: LN-of-products closed form, write agg ----
  const float inv = 1.f / den;
  const float4 g4 = *(const float4*)&g_sm[da * 4];
  const float4 b4 = *(const float4*)&b_sm[da * 4];
  float4 o;
  o.x = fmaf(g4.x, (acc.x - c) * inv, b4.x);
  o.y = fmaf(g4.y, (acc.y - c) * inv, b4.y);
  o.z = fmaf(g4.z, (acc.z - c) * inv, b4.z);
  o.w = fmaf(g4.w, (acc.w - c) * inv, b4.w);
  *(float4*)&agg[((size_t)(X * NTOK + yy)) * EMBED + H * HD + da * 4] = o;
}

// ---------------- K3: out = LN([x, agg] @ Wf + bf) ----------------
__global__ __launch_bounds__(256) void k_final(
    const float* __restrict__ x, const float* __restrict__ agg,
    const float* __restrict__ Wf, const float* __restrict__ bf,
    const float* __restrict__ g2, const float* __restrict__ b2,
    float* __restrict__ out) {
  const int r0 = blockIdx.x * RPB;
  const int tid = threadIdx.x;
  const int e = tid & 127;
  const int rg = tid >> 7;               // row group: 8 rows each
  __shared__ float ct[2 * EMBED][20];    // transposed [x|agg], stride 20
  __shared__ float red[2][8][2][2];

  #pragma unroll
  for (int k = 0; k < RPB; ++k) {
    const float v = (tid < EMBED) ? x[(size_t)(r0 + k) * EMBED + tid]
                                  : agg[(size_t)(r0 + k) * EMBED + (tid - EMBED)];
    ct[tid][k] = v;
  }
  __syncthreads();

  float acc[8];
  const float bias = bf[e];
  #pragma unroll
  for (int k = 0; k < 8; ++k) acc[k] = bias;

  #pragma unroll 4
  for (int i = 0; i < 2 * EMBED; ++i) {
    const float wv = Wf[(size_t)i * EMBED + e];
    const float4 c0 = *(const float4*)&ct[i][rg * 8];
    const float4 c1 = *(const float4*)&ct[i][rg * 8 + 4];
    acc[0] = fmaf(wv, c0.x, acc[0]); acc[1] = fmaf(wv, c0.y, acc[1]);
    acc[2] = fmaf(wv, c0.z, acc[2]); acc[3] = fmaf(wv, c0.w, acc[3]);
    acc[4] = fmaf(wv, c1.x, acc[4]); acc[5] = fmaf(wv, c1.y, acc[5]);
    acc[6] = fmaf(wv, c1.z, acc[6]); acc[7] = fmaf(wv, c1.w, acc[7]);
  }

  const int wh = (tid >> 6) & 1;
  #pragma unroll
  for (int k = 0; k < 8; ++k) {
    float s1 = acc[k], s2 = acc[k] * acc[k];
    #pragma unroll
    for (int m_ = 1; m_ < 64; m_ <<= 1) {
      s1 += __shfl_xor(s1, m_, 64);
      s2 += __shfl_xor(s2, m_, 64);
    }
    if ((tid & 63) == 0) { red[rg][k][wh][0] = s1; red[rg][k][wh][1] = s2; }
  }
  __syncthreads();

  const float gg = g2[e], bb = b2[e];
  #pragma unroll
  for (int k = 0; k < 8; ++k) {
    const float S1 = red[rg][k][0][0] + red[rg][k][1][0];
    const float S2 = red[rg][k][0][1] + red[rg][k][1][1];
    const float mu = S1 * (1.f / EMBED);
    const float var = S2 * (1.f / EMBED) - mu * mu;
    const float rstd = rsqrtf(var + 1e-5f);
    out[(size_t)(r0 + rg * 8 + k) * EMBED + e] = (acc[k] - mu) * rstd * gg + bb;
  }
}

extern "C" void kernel_launch(void* const* d_in, const int* in_sizes, int n_in,
                              void* d_out, int out_size, void* d_ws, size_t ws_size,
                              hipStream_t stream) {
  const float* x    = (const float*)d_in[0];
  const float* W    = (const float*)d_in[1];
  const float* b    = (const float*)d_in[2];
  const float* ln_g = (const float*)d_in[3];
  const float* ln_b = (const float*)d_in[4];
  const float* Wf   = (const float*)d_in[5];
  const float* bf   = (const float*)d_in[6];
  const float* g2   = (const float*)d_in[7];
  const float* b2   = (const float*)d_in[8];
  float* out = (float*)d_out;

  float* pT   = (float*)d_ws;                         // NROW*128
  float* murT = pT + (size_t)NROW * EMBED;            // NROW*4*2
  float* agg  = murT + (size_t)NROW * HEADS * 2;      // NROW*128

  k_proj<<<NBLK, 128, 0, stream>>>(x, W, b, pT, murT);
  k_attn<<<NTOK * NYT * 2, 256, 0, stream>>>(pT, murT, ln_g, ln_b, agg);
  k_final<<<NBLK, 256, 0, stream>>>(x, agg, Wf, bf, g2, b2, out);
}

// Round 5
// 112.610 us; speedup vs baseline: 3.2940x; 1.3713x over previous
//
#include <hip/hip_runtime.h>
#include <math.h>

#define NTOK 96
#define EMBED 128
#define HEADS 4
#define HD 32
#define NROW (NTOK*NTOK)     // 9216
#define YT 16
#define NYT (NTOK/YT)        // 6

// ---------------- K1: pT[(y*96+x)] = row(x,y) of x@W+b ; murT stats ----------------
// 2304 blocks x 128 threads, 4 rows per block
__global__ __launch_bounds__(128) void k_proj(
    const float* __restrict__ x, const float* __restrict__ W,
    const float* __restrict__ b,
    float* __restrict__ pT, float* __restrict__ murT) {
  const int r0 = blockIdx.x * 4;         // global row = X*96 + y
  const int X  = r0 / NTOK;
  const int y0 = r0 % NTOK;
  const int e  = threadIdx.x;            // 0..127
  __shared__ float xt[EMBED][4];
  #pragma unroll
  for (int k = 0; k < 4; ++k)
    xt[e][k] = x[(size_t)(r0 + k) * EMBED + e];
  __syncthreads();

  const float bias = b[e];
  float a0 = bias, a1 = bias, a2 = bias, a3 = bias;
  #pragma unroll 8
  for (int i = 0; i < EMBED; ++i) {
    const float wv = W[(size_t)i * EMBED + e];
    const float4 c = *(const float4*)&xt[i][0];
    a0 = fmaf(wv, c.x, a0); a1 = fmaf(wv, c.y, a1);
    a2 = fmaf(wv, c.z, a2); a3 = fmaf(wv, c.w, a3);
  }

  const int h = e >> 5;
  float accs[4] = {a0, a1, a2, a3};
  #pragma unroll
  for (int k = 0; k < 4; ++k) {
    pT[((size_t)(y0 + k) * NTOK + X) * EMBED + e] = accs[k];
    float s1 = accs[k], s2 = accs[k] * accs[k];
    #pragma unroll
    for (int m_ = 1; m_ < 32; m_ <<= 1) {
      s1 += __shfl_xor(s1, m_, 64);
      s2 += __shfl_xor(s2, m_, 64);
    }
    if ((e & 31) == 0) {
      const float mu = s1 * (1.f / HD);
      const float var = fmaxf(s2 * (1.f / HD) - mu * mu, 0.f);
      float2 v; v.x = mu; v.y = rsqrtf(var + 1e-5f);
      *(float2*)&murT[(((size_t)(y0 + k) * NTOK + X) * HEADS + h) * 2] = v;
    }
  }
}

__device__ __forceinline__ void sc_elem(float e, float f, float g, float b,
    float rE, float pE, float rF, float pF,
    float& s, float& m, float& q, float& t) {
  const float uE = fmaf(e, rE, -pE);
  const float en = fmaf(uE, g, b);
  const float uF = fmaf(f, rF, -pF);
  const float fn = fmaf(uF, g, b);
  s = fmaf(en, fn, s);
  t = e * f;
  m += t;
  q = fmaf(t, t, q);
}

#define SC_QUAD(E4, F4, G4, B4, T4) \
  sc_elem(E4.x, F4.x, G4.x, B4.x, rE, pE, rF, pF, s, m, q, T4.x); \
  sc_elem(E4.y, F4.y, G4.y, B4.y, rE, pE, rF, pF, s, m, q, T4.y); \
  sc_elem(E4.z, F4.z, G4.z, B4.z, rE, pE, rF, pF, s, m, q, T4.z); \
  sc_elem(E4.w, F4.w, G4.w, B4.w, rE, pE, rF, pF, s, m, q, T4.w);

#define AGG_QUAD(A4, T4) \
  A4.x = fmaf(w, T4.x, A4.x); A4.y = fmaf(w, T4.y, A4.y); \
  A4.z = fmaf(w, T4.z, A4.z); A4.w = fmaf(w, T4.w, A4.w);

#define SCALE_QUAD(A4) \
  A4.x *= scale; A4.y *= scale; A4.z *= scale; A4.w *= scale;

#define RED_QUAD(A4, MASK) \
  A4.x += __shfl_xor(A4.x, MASK, 64); A4.y += __shfl_xor(A4.y, MASK, 64); \
  A4.z += __shfl_xor(A4.z, MASK, 64); A4.w += __shfl_xor(A4.w, MASK, 64);

// ---------------- K2: fused attention + product-LN agg + final GEMM + LN ----------------
// 576 blocks (X:96, ytile:6) x 256 threads = (y:16, ds:2, da:8); heads looped.
__global__ __launch_bounds__(256) void k_fused(
    const float* __restrict__ pT, const float* __restrict__ murT,
    const float* __restrict__ ln_g, const float* __restrict__ ln_b,
    const float* __restrict__ x, const float* __restrict__ Wf,
    const float* __restrict__ bf, const float* __restrict__ g2,
    const float* __restrict__ b2, float* __restrict__ out) {
  const int bid = blockIdx.x;
  const int X   = bid / NYT;
  const int y0  = (bid % NYT) * YT;

  const int tid = threadIdx.x;
  const int y   = tid >> 4;
  const int t16 = tid & 15;
  const int ds  = t16 >> 3;      // d-half
  const int da  = t16 & 7;       // a-slice
  const int yy  = y0 + y;
  const int eoff = ds * 16;

  __shared__ float e_sm[NTOK][36];     // per-head e slice, 13.8 KB
  __shared__ float mur_sm[NTOK][2];    // per-head e-row stats
  __shared__ float xt_sm[EMBED][20];   // x rows transposed [c][y]
  __shared__ float agg_t[EMBED][20];   // agg transposed [d][y]
  __shared__ float g_sm[HD], b_sm[HD];
  __shared__ float red_sm[4][8][2];

  // stage x rows (transposed): coalesced in c
  #pragma unroll
  for (int i = 0; i < 8; ++i) {
    const int g = tid + i * 256;       // 0..2047
    const int yl = g >> 7, c = g & 127;
    xt_sm[c][yl] = x[((size_t)(X * NTOK + y0 + yl)) * EMBED + c];
  }
  if (tid < HD) { g_sm[tid] = ln_g[tid]; b_sm[tid] = ln_b[tid]; }

  for (int H = 0; H < HEADS; ++H) {
    __syncthreads();   // protect e_sm/mur_sm from previous head's readers
    #pragma unroll
    for (int i = 0; i < 3; ++i) {
      const int g = tid + i * 256;     // 0..767
      const int a = g >> 3, qq = g & 7;
      *(float4*)&e_sm[a][qq * 4] =
          *(const float4*)&pT[((size_t)a * NTOK + X) * EMBED + H * HD + qq * 4];
    }
    if (tid < NTOK) {
      const float2 v = *(const float2*)&murT[(((size_t)tid * NTOK + X) * HEADS + H) * 2];
      mur_sm[tid][0] = v.x; mur_sm[tid][1] = v.y;
    }
    __syncthreads();

    const float4 g0 = *(const float4*)&g_sm[eoff];
    const float4 g1 = *(const float4*)&g_sm[eoff + 4];
    const float4 g2v = *(const float4*)&g_sm[eoff + 8];
    const float4 g3 = *(const float4*)&g_sm[eoff + 12];
    const float4 b0 = *(const float4*)&b_sm[eoff];
    const float4 b1 = *(const float4*)&b_sm[eoff + 4];
    const float4 b2v = *(const float4*)&b_sm[eoff + 8];
    const float4 b3 = *(const float4*)&b_sm[eoff + 12];

    const float* fbase = pT + (size_t)yy * NTOK * EMBED + H * HD + eoff;
    const float* mbase = murT + ((size_t)yy * NTOK * HEADS + H) * 2;

    float4 acc0 = {0,0,0,0}, acc1 = {0,0,0,0}, acc2 = {0,0,0,0}, acc3 = {0,0,0,0};
    float den = 0.f, c = 0.f, mx = -1e30f;

    #pragma unroll 2
    for (int ia = 0; ia < 12; ++ia) {
      const int a = ia * 8 + da;
      const float4* fp = (const float4*)(fbase + (size_t)a * EMBED);
      const float4 f0 = fp[0], f1 = fp[1], f2 = fp[2], f3 = fp[3];
      const float2 mrF = *(const float2*)(mbase + (size_t)a * (HEADS * 2));
      const float muE = mur_sm[a][0], rE = mur_sm[a][1];
      const float rF = mrF.y;
      const float pE = muE * rE;
      const float pF = mrF.x * rF;
      const float4 e0 = *(const float4*)&e_sm[a][eoff];
      const float4 e1 = *(const float4*)&e_sm[a][eoff + 4];
      const float4 e2 = *(const float4*)&e_sm[a][eoff + 8];
      const float4 e3 = *(const float4*)&e_sm[a][eoff + 12];

      float s = 0.f, m = 0.f, q = 0.f;
      float4 t0, t1, t2, t3;
      SC_QUAD(e0, f0, g0, b0, t0);
      SC_QUAD(e1, f1, g1, b1, t1);
      SC_QUAD(e2, f2, g2v, b2v, t2);
      SC_QUAD(e3, f3, g3, b3, t3);

      // combine d-halves (xor ds bit)
      s += __shfl_xor(s, 8, 64);
      m += __shfl_xor(m, 8, 64);
      q += __shfl_xor(q, 8, 64);

      const float mu = m * (1.f / HD);
      const float var = fmaxf(fmaf(-mu, mu, q * (1.f / HD)), 0.f);
      const float r = rsqrtf(var + 1e-5f);
      const float sc = s * 0.17677669529663687f;  // 1/sqrt(32)

      // online max over the 8 a's of this iteration (uniform in 16-lane group)
      float mc = sc;
      mc = fmaxf(mc, __shfl_xor(mc, 1, 64));
      mc = fmaxf(mc, __shfl_xor(mc, 2, 64));
      mc = fmaxf(mc, __shfl_xor(mc, 4, 64));
      const float nmx = fmaxf(mx, mc);
      const float scale = __expf(mx - nmx);
      mx = nmx;
      const float ex = __expf(sc - mx);
      const float w = ex * r;
      den = fmaf(den, scale, ex);
      c   = fmaf(c,   scale, w * mu);
      SCALE_QUAD(acc0); SCALE_QUAD(acc1); SCALE_QUAD(acc2); SCALE_QUAD(acc3);
      AGG_QUAD(acc0, t0);
      AGG_QUAD(acc1, t1);
      AGG_QUAD(acc2, t2);
      AGG_QUAD(acc3, t3);
    }

    // cross-a reduction over the 8 da lanes
    #pragma unroll
    for (int mask = 1; mask <= 4; mask <<= 1) {
      den += __shfl_xor(den, mask, 64);
      c   += __shfl_xor(c,   mask, 64);
      RED_QUAD(acc0, mask);
      RED_QUAD(acc1, mask);
      RED_QUAD(acc2, mask);
      RED_QUAD(acc3, mask);
    }

    if (da == 0) {
      const float inv = 1.f / den;
      float ov[16];
      ov[0]  = fmaf(g0.x, (acc0.x - c) * inv, b0.x);
      ov[1]  = fmaf(g0.y, (acc0.y - c) * inv, b0.y);
      ov[2]  = fmaf(g0.z, (acc0.z - c) * inv, b0.z);
      ov[3]  = fmaf(g0.w, (acc0.w - c) * inv, b0.w);
      ov[4]  = fmaf(g1.x, (acc1.x - c) * inv, b1.x);
      ov[5]  = fmaf(g1.y, (acc1.y - c) * inv, b1.y);
      ov[6]  = fmaf(g1.z, (acc1.z - c) * inv, b1.z);
      ov[7]  = fmaf(g1.w, (acc1.w - c) * inv, b1.w);
      ov[8]  = fmaf(g2v.x, (acc2.x - c) * inv, b2v.x);
      ov[9]  = fmaf(g2v.y, (acc2.y - c) * inv, b2v.y);
      ov[10] = fmaf(g2v.z, (acc2.z - c) * inv, b2v.z);
      ov[11] = fmaf(g2v.w, (acc2.w - c) * inv, b2v.w);
      ov[12] = fmaf(g3.x, (acc3.x - c) * inv, b3.x);
      ov[13] = fmaf(g3.y, (acc3.y - c) * inv, b3.y);
      ov[14] = fmaf(g3.z, (acc3.z - c) * inv, b3.z);
      ov[15] = fmaf(g3.w, (acc3.w - c) * inv, b3.w);
      #pragma unroll
      for (int j = 0; j < 16; ++j)
        agg_t[H * HD + eoff + j][y] = ov[j];
    }
  }
  __syncthreads();   // agg_t complete

  // ---- final: out = LN([x, agg] @ Wf + bf) over the block's 16 rows ----
  const int e  = tid & 127;
  const int rh = tid >> 7;            // 8 rows each
  const float bias = bf[e];
  float acc8[8];
  #pragma unroll
  for (int k = 0; k < 8; ++k) acc8[k] = bias;

  #pragma unroll 4
  for (int i = 0; i < EMBED; ++i) {
    const float wv = Wf[(size_t)i * EMBED + e];
    const float4 c0 = *(const float4*)&xt_sm[i][rh * 8];
    const float4 c1 = *(const float4*)&xt_sm[i][rh * 8 + 4];
    acc8[0] = fmaf(wv, c0.x, acc8[0]); acc8[1] = fmaf(wv, c0.y, acc8[1]);
    acc8[2] = fmaf(wv, c0.z, acc8[2]); acc8[3] = fmaf(wv, c0.w, acc8[3]);
    acc8[4] = fmaf(wv, c1.x, acc8[4]); acc8[5] = fmaf(wv, c1.y, acc8[5]);
    acc8[6] = fmaf(wv, c1.z, acc8[6]); acc8[7] = fmaf(wv, c1.w, acc8[7]);
  }
  #pragma unroll 4
  for (int i = 0; i < EMBED; ++i) {
    const float wv = Wf[(size_t)(EMBED + i) * EMBED + e];
    const float4 c0 = *(const float4*)&agg_t[i][rh * 8];
    const float4 c1 = *(const float4*)&agg_t[i][rh * 8 + 4];
    acc8[0] = fmaf(wv, c0.x, acc8[0]); acc8[1] = fmaf(wv, c0.y, acc8[1]);
    acc8[2] = fmaf(wv, c0.z, acc8[2]); acc8[3] = fmaf(wv, c0.w, acc8[3]);
    acc8[4] = fmaf(wv, c1.x, acc8[4]); acc8[5] = fmaf(wv, c1.y, acc8[5]);
    acc8[6] = fmaf(wv, c1.z, acc8[6]); acc8[7] = fmaf(wv, c1.w, acc8[7]);
  }

  const int wid = tid >> 6;
  #pragma unroll
  for (int k = 0; k < 8; ++k) {
    float s1 = acc8[k], s2 = acc8[k] * acc8[k];
    #pragma unroll
    for (int m_ = 1; m_ < 64; m_ <<= 1) {
      s1 += __shfl_xor(s1, m_, 64);
      s2 += __shfl_xor(s2, m_, 64);
    }
    if ((tid & 63) == 0) { red_sm[wid][k][0] = s1; red_sm[wid][k][1] = s2; }
  }
  __syncthreads();

  const float gg = g2[e], bb = b2[e];
  #pragma unroll
  for (int k = 0; k < 8; ++k) {
    const float S1 = red_sm[wid][k][0] + red_sm[wid ^ 1][k][0];
    const float S2 = red_sm[wid][k][1] + red_sm[wid ^ 1][k][1];
    const float mu = S1 * (1.f / EMBED);
    const float var = fmaxf(S2 * (1.f / EMBED) - mu * mu, 0.f);
    const float rstd = rsqrtf(var + 1e-5f);
    out[((size_t)(X * NTOK + y0 + rh * 8 + k)) * EMBED + e] =
        (acc8[k] - mu) * rstd * gg + bb;
  }
}

extern "C" void kernel_launch(void* const* d_in, const int* in_sizes, int n_in,
                              void* d_out, int out_size, void* d_ws, size_t ws_size,
                              hipStream_t stream) {
  const float* x    = (const float*)d_in[0];
  const float* W    = (const float*)d_in[1];
  const float* b    = (const float*)d_in[2];
  const float* ln_g = (const float*)d_in[3];
  const float* ln_b = (const float*)d_in[4];
  const float* Wf   = (const float*)d_in[5];
  const float* bf   = (const float*)d_in[6];
  const float* g2   = (const float*)d_in[7];
  const float* b2   = (const float*)d_in[8];
  float* out = (float*)d_out;

  float* pT   = (float*)d_ws;                         // NROW*128
  float* murT = pT + (size_t)NROW * EMBED;            // NROW*4*2

  k_proj<<<NROW / 4, 128, 0, stream>>>(x, W, b, pT, murT);
  k_fused<<<NTOK * NYT, 256, 0, stream>>>(pT, murT, ln_g, ln_b,
                                          x, Wf, bf, g2, b2, out);
}